// Round 8
// baseline (130.078 us; speedup 1.0000x reference)
//
#include <hip/hip_runtime.h>

#define B_ 2
#define S_ 2048
#define D_ 1024
#define H_ 16
#define HW_ 64
#define NT_ (S_ / 64)
#define NSPLIT_ 2
#define TPS_ (NT_ / NSPLIT_)  // tiles per split = 16

typedef __attribute__((ext_vector_type(8))) short s16x8;
typedef __attribute__((ext_vector_type(4))) float f32x4;
typedef __attribute__((ext_vector_type(2))) unsigned int u32x2;
typedef __attribute__((ext_vector_type(4))) unsigned int u32x4;

__device__ __forceinline__ unsigned short f2bf(float f) {
  unsigned int x = __builtin_bit_cast(unsigned int, f);
  x += 0x7fffu + ((x >> 16) & 1u);
  return (unsigned short)(x >> 16);
}
__device__ __forceinline__ unsigned int cvtpk_bf16(float lo, float hi) {
  unsigned int r;
  asm("v_cvt_pk_bf16_f32 %0, %1, %2" : "=v"(r) : "v"(lo), "v"(hi));
  return r;
}
__device__ __forceinline__ void gload16(const void* g, void* l) {
  __builtin_amdgcn_global_load_lds(
      (const __attribute__((address_space(1))) unsigned int*)g,
      (__attribute__((address_space(3))) unsigned int*)l, 16, 0, 0);
}

// ---------------- unified convert: x | wq/wk/wv | pos+mask ------------------
__global__ __launch_bounds__(256) void cvt_all(const float* __restrict__ x,
                                               const float* __restrict__ wq,
                                               const float* __restrict__ wk,
                                               const float* __restrict__ wv,
                                               const float* __restrict__ pos,
                                               const int* __restrict__ mask,
                                               unsigned short* __restrict__ xb,
                                               unsigned short* __restrict__ wb,
                                               unsigned short* __restrict__ posb) {
  const int blk = blockIdx.x;
  if (blk < 2048) {
    int i = blk * 256 + threadIdx.x;
    const float4* s = (const float4*)x;
    float4 a = s[2 * i], b = s[2 * i + 1];
    s16x8 o;
    o[0] = (short)f2bf(a.x); o[1] = (short)f2bf(a.y);
    o[2] = (short)f2bf(a.z); o[3] = (short)f2bf(a.w);
    o[4] = (short)f2bf(b.x); o[5] = (short)f2bf(b.y);
    o[6] = (short)f2bf(b.z); o[7] = (short)f2bf(b.w);
    ((s16x8*)xb)[i] = o;
  } else if (blk < 3584) {
    int blk2 = blk - 2048;
    const float* src = (blk2 < 512) ? wq : (blk2 < 1024) ? wk : wv;
    int i = (blk2 & 511) * 256 + threadIdx.x;
    const float4* s = (const float4*)src;
    float4 a = s[2 * i], b = s[2 * i + 1];
    s16x8 o;
    o[0] = (short)f2bf(a.x); o[1] = (short)f2bf(a.y);
    o[2] = (short)f2bf(a.z); o[3] = (short)f2bf(a.w);
    o[4] = (short)f2bf(b.x); o[5] = (short)f2bf(b.y);
    o[6] = (short)f2bf(b.z); o[7] = (short)f2bf(b.w);
    ((s16x8*)wb)[(size_t)(blk2 >> 9) * (D_ * D_ / 8) + i] = o;
  } else {
    int i = (blk - 3584) * 256 + threadIdx.x;  // 8 elems per thread
    int e = i * 8;
    int b = e / (S_ * S_);
    int k = e & (S_ - 1);
    const float4* s = (const float4*)pos;
    float4 a = s[2 * i], c = s[2 * i + 1];
    const int* mrow = mask + b * S_ + k;
    const float L2E = 1.4426950408889634f;
    float f[8] = {a.x, a.y, a.z, a.w, c.x, c.y, c.z, c.w};
    s16x8 o;
#pragma unroll
    for (int j = 0; j < 8; ++j) {
      float bias = mrow[j] ? 0.0f : -14427.0f;
      o[j] = (short)f2bf(f[j] * L2E + bias);
    }
    ((s16x8*)posb)[i] = o;
  }
}

// ---------------- QKV projection GEMM: C = X(bf16) * W^T + bias -------------
// mat==0 (Q): output pre-scaled by 0.125*log2e.  mat==2 (V): operands swapped
// -> epilogue writes V directly TRANSPOSED to VT[b][h][d][s].
__global__ __launch_bounds__(256) void qkv_gemm(const unsigned short* __restrict__ X,
                                                const unsigned short* __restrict__ W3,
                                                const float* __restrict__ bq,
                                                const float* __restrict__ bk,
                                                const float* __restrict__ bv,
                                                unsigned short* __restrict__ O3,
                                                unsigned short* __restrict__ VT) {
  const int mat = blockIdx.z;
  const unsigned short* Wp = W3 + (size_t)mat * (D_ * D_);
  const float* bias = (mat == 0) ? bq : (mat == 1) ? bk : bv;
  unsigned short* Op = O3 + (size_t)mat * ((size_t)B_ * S_ * D_);

  const int bm = blockIdx.y * 128, bn = blockIdx.x * 128;
  const int tid = threadIdx.x;
  const int lane = tid & 63, w = tid >> 6;
  const int wr = (w >> 1) * 64, wc = (w & 1) * 64;
  const int l15 = lane & 15, lh = lane >> 4;

  __shared__ __align__(16) unsigned short Al[128 * 64];
  __shared__ __align__(16) unsigned short Wl[128 * 64];

  f32x4 acc[4][4];
#pragma unroll
  for (int m = 0; m < 4; ++m)
#pragma unroll
    for (int n = 0; n < 4; ++n) acc[m][n] = (f32x4){0.f, 0.f, 0.f, 0.f};

  const int srow = lane >> 3;
  const int scol = ((lane & 7) ^ srow) * 8;
  const int i0 = w * 4;

  for (int k0 = 0; k0 < D_; k0 += 64) {
    __syncthreads();
#pragma unroll
    for (int i2 = 0; i2 < 4; ++i2) {
      int i = i0 + i2;
      int row = 8 * i + srow;
      gload16(X + (size_t)(bm + row) * D_ + k0 + scol, Al + i * 512);
      gload16(Wp + (size_t)(bn + row) * D_ + k0 + scol, Wl + i * 512);
    }
    __syncthreads();
#pragma unroll
    for (int kb = 0; kb < 2; ++kb) {
      const int cs = (kb * 32 + lh * 8) ^ ((l15 & 7) * 8);
      s16x8 af[4], wf[4];
#pragma unroll
      for (int m = 0; m < 4; ++m)
        af[m] = *(const s16x8*)(Al + (wr + m * 16 + l15) * 64 + cs);
#pragma unroll
      for (int n = 0; n < 4; ++n)
        wf[n] = *(const s16x8*)(Wl + (wc + n * 16 + l15) * 64 + cs);
      if (mat == 2) {
#pragma unroll
        for (int m = 0; m < 4; ++m)
#pragma unroll
          for (int n = 0; n < 4; ++n)
            acc[m][n] =
                __builtin_amdgcn_mfma_f32_16x16x32_bf16(wf[n], af[m], acc[m][n], 0, 0, 0);
      } else {
#pragma unroll
        for (int m = 0; m < 4; ++m)
#pragma unroll
          for (int n = 0; n < 4; ++n)
            acc[m][n] =
                __builtin_amdgcn_mfma_f32_16x16x32_bf16(af[m], wf[n], acc[m][n], 0, 0, 0);
      }
    }
  }

  if (mat == 2) {
#pragma unroll
    for (int n = 0; n < 4; ++n) {
      f32x4 b4 = *(const f32x4*)(bias + bn + wc + n * 16 + lh * 4);
#pragma unroll
      for (int m = 0; m < 4; ++m) {
        int t = bm + wr + m * 16 + l15;  // global token
        int bb = t >> 11, s = t & (S_ - 1);
#pragma unroll
        for (int r = 0; r < 4; ++r) {
          int f = bn + wc + n * 16 + lh * 4 + r;  // global feature
          VT[((size_t)(bb * H_ + (f >> 6)) * HW_ + (f & 63)) * S_ + s] =
              f2bf(acc[m][n][r] + b4[r]);
        }
      }
    }
  } else {
    const float oscale = (mat == 0) ? 0.18033688751411092f : 1.0f;  // 0.125*log2e
#pragma unroll
    for (int n = 0; n < 4; ++n) {
      int col = bn + wc + n * 16 + l15;
      float bval = bias[col];
#pragma unroll
      for (int m = 0; m < 4; ++m) {
        int row0 = bm + wr + m * 16 + lh * 4;
#pragma unroll
        for (int r = 0; r < 4; ++r)
          Op[(size_t)(row0 + r) * D_ + col] = f2bf((acc[m][n][r] + bval) * oscale);
      }
    }
  }
}

// ---------------- fused flash attention (split-K over key range) ------------
// grid (H, S/64, B*NSPLIT): z = sp*B + b. Each block does 16 KV tiles.
// Max-free softmax => partials are purely additive: sp==1 writes unnormalized
// O (f32) to OUT, sp==0 to OP0; per-row l to LP[sp][b][h][q]. combine() joins.
__global__ __launch_bounds__(256, 4) void attn_kernel(
    const unsigned short* __restrict__ Q,
    const unsigned short* __restrict__ K,
    const unsigned short* __restrict__ VT,
    const unsigned short* __restrict__ POSM,
    float* __restrict__ OP0,
    float* __restrict__ LP,
    float* __restrict__ OUT) {
  const int h = blockIdx.x, qt = blockIdx.y;
  const int b = blockIdx.z & (B_ - 1), sp = blockIdx.z >> 1;
  const int tid = threadIdx.x;
  const int lane = tid & 63, w = tid >> 6;
  const int l15 = lane & 15, lh = lane >> 4;

  __shared__ __align__(16) unsigned short Kl[2][64 * 64];  // [key][d], swizzled
  __shared__ __align__(16) unsigned short Vl[2][64 * 64];  // [d][key], swizzled

  const int swzk = ((l15 & 3) | (((l15 >> 2) & 1) << 2)) * 8;
  const int swzv = ((l15 & 3) | ((l15 & 8) >> 1)) * 8;
  const int rowbase = 8 * (l15 >> 2) + (l15 & 3);

  const int srow = lane >> 3;
  const int scol = ((lane & 7) ^ ((lane >> 3) & 3) ^ ((w & 1) << 2)) * 8;
  const unsigned short* Kbase = K + (size_t)b * S_ * D_ + h * HW_;
  const unsigned short* Vbase = VT + ((size_t)(b * H_ + h) * HW_) * S_;

  auto stage = [&](int buf, int kt) {
    const int k0 = kt * 64;
#pragma unroll
    for (int i = 0; i < 2; ++i) {
      const int rb = i * 32 + w * 8;
      gload16(Kbase + (size_t)(k0 + rb + srow) * D_ + scol, &Kl[buf][rb * 64]);
      gload16(Vbase + (size_t)(rb + srow) * S_ + k0 + scol, &Vl[buf][rb * 64]);
    }
  };

  const int kt0 = sp * TPS_;
  const int q0 = qt * 64 + w * 16;
  const int qg = q0 + l15;
  const unsigned short* Pp = POSM + (size_t)(b * S_ + qg) * S_ + lh * 8;

  // prologue: pos tile kt0 + stage tile kt0
  u32x2 pmw_c[4], pmw_n[4];
#pragma unroll
  for (int n = 0; n < 4; ++n)
    pmw_c[n] = *(const u32x2*)(Pp + kt0 * 64 + (n >> 1) * 32 + (n & 1) * 4);
  stage(0, kt0);

  s16x8 qf[2];
  {
    const unsigned short* qp = Q + (size_t)(b * S_ + qg) * D_ + h * HW_ + lh * 8;
    qf[0] = *(const s16x8*)qp;
    qf[1] = *(const s16x8*)(qp + 32);
  }

  f32x4 Oc[4];
#pragma unroll
  for (int n = 0; n < 4; ++n) Oc[n] = (f32x4){0.f, 0.f, 0.f, 0.f};
  f32x4 lsum = (f32x4){0.f, 0.f, 0.f, 0.f};

  for (int t = 0; t < TPS_; ++t) {
    const int kt = kt0 + t;
    const int cur = t & 1;

    if (t + 1 < TPS_) {
#pragma unroll
      for (int n = 0; n < 4; ++n)
        pmw_n[n] = *(const u32x2*)(Pp + (kt + 1) * 64 + (n >> 1) * 32 + (n & 1) * 4);
      stage(cur ^ 1, kt + 1);
      // queue oldest->newest: stage(kt)[4] | pos(kt+1)[4] stage(kt+1)[4]
      asm volatile("s_waitcnt vmcnt(8)" ::: "memory");
    } else {
      asm volatile("s_waitcnt vmcnt(0)" ::: "memory");
    }
    asm volatile("s_barrier" ::: "memory");

    const unsigned short* Kc = Kl[cur];
    const unsigned short* Vc = Vl[cur];

    // QK^T (swapped, key-permuted): sc[n][r] -> key = (n>>1)*32 + lh*8 + (n&1)*4 + r
    f32x4 sc[4];
    __builtin_amdgcn_s_setprio(1);
#pragma unroll
    for (int n = 0; n < 4; ++n) {
      const unsigned short* kr = Kc + (rowbase + (n & 1) * 4 + (n >> 1) * 32) * 64;
      s16x8 kf0 = *(const s16x8*)(kr + ((lh * 8) ^ swzk));
      s16x8 kf1 = *(const s16x8*)(kr + ((32 + lh * 8) ^ swzk));
      f32x4 c;
      c[0] = __builtin_bit_cast(float, pmw_c[n][0] << 16);
      c[1] = __builtin_bit_cast(float, pmw_c[n][0] & 0xffff0000u);
      c[2] = __builtin_bit_cast(float, pmw_c[n][1] << 16);
      c[3] = __builtin_bit_cast(float, pmw_c[n][1] & 0xffff0000u);
      c = __builtin_amdgcn_mfma_f32_16x16x32_bf16(kf0, qf[0], c, 0, 0, 0);
      c = __builtin_amdgcn_mfma_f32_16x16x32_bf16(kf1, qf[1], c, 0, 0, 0);
      sc[n] = c;
    }
    __builtin_amdgcn_s_setprio(0);

    // p = exp2(score) directly; accumulate per-lane partial sums
#pragma unroll
    for (int n = 0; n < 4; ++n)
#pragma unroll
      for (int r = 0; r < 4; ++r) {
        float p = __builtin_amdgcn_exp2f(sc[n][r]);
        sc[n][r] = p;
        lsum[n] += p;
      }

    // PV: B-fragment built in registers (keys kb*32 + lh*8 + 0..7)
    __builtin_amdgcn_s_setprio(1);
#pragma unroll
    for (int kb = 0; kb < 2; ++kb) {
      u32x4 pw;
      pw[0] = cvtpk_bf16(sc[2 * kb][0], sc[2 * kb][1]);
      pw[1] = cvtpk_bf16(sc[2 * kb][2], sc[2 * kb][3]);
      pw[2] = cvtpk_bf16(sc[2 * kb + 1][0], sc[2 * kb + 1][1]);
      pw[3] = cvtpk_bf16(sc[2 * kb + 1][2], sc[2 * kb + 1][3]);
      s16x8 pf = __builtin_bit_cast(s16x8, pw);
#pragma unroll
      for (int n = 0; n < 4; ++n) {
        s16x8 vf = *(const s16x8*)(Vc + (n * 16 + l15) * 64 + ((kb * 32 + lh * 8) ^ swzv));
        Oc[n] = __builtin_amdgcn_mfma_f32_16x16x32_bf16(vf, pf, Oc[n], 0, 0, 0);
      }
    }
    __builtin_amdgcn_s_setprio(0);

    asm volatile("s_barrier" ::: "memory");

#pragma unroll
    for (int n = 0; n < 4; ++n) pmw_c[n] = pmw_n[n];
  }

  // epilogue: reduce l across lh groups; store UNNORMALIZED partial O + l
  float lrow = (lsum[0] + lsum[1]) + (lsum[2] + lsum[3]);
  lrow += __shfl_xor(lrow, 16, 64);
  lrow += __shfl_xor(lrow, 32, 64);
  if (lh == 0)
    LP[(size_t)sp * (B_ * H_ * S_) + ((size_t)b * H_ + h) * S_ + qg] = lrow;

  float* outp = (sp ? OUT : OP0) + (size_t)(b * S_ + qg) * D_ + h * HW_ + lh * 4;
#pragma unroll
  for (int n = 0; n < 4; ++n)
    *(f32x4*)(outp + n * 16) = Oc[n];
}

// ---------------- combine: OUT = (OP0 + OUT) / (l0 + l1) --------------------
__global__ __launch_bounds__(256) void combine_kernel(const float* __restrict__ OP0,
                                                      const float* __restrict__ LP,
                                                      float* __restrict__ OUT) {
  int i = blockIdx.x * 256 + threadIdx.x;  // 8 floats per thread
  int e = i * 8;
  int bb = e >> 21;                 // S*D = 2^21 per batch
  int s = (e >> 10) & (S_ - 1);
  int h = (e & (D_ - 1)) >> 6;
  size_t li = ((size_t)bb * H_ + h) * S_ + s;
  float l0 = LP[li];
  float l1 = LP[(size_t)(B_ * H_ * S_) + li];
  float inv = 1.0f / (l0 + l1);
  f32x4 a0 = *(const f32x4*)(OP0 + e), a1 = *(const f32x4*)(OP0 + e + 4);
  f32x4 b0 = *(const f32x4*)(OUT + e), b1 = *(const f32x4*)(OUT + e + 4);
#pragma unroll
  for (int r = 0; r < 4; ++r) { b0[r] = (a0[r] + b0[r]) * inv; b1[r] = (a1[r] + b1[r]) * inv; }
  *(f32x4*)(OUT + e) = b0;
  *(f32x4*)(OUT + e + 4) = b1;
}

// ---------------- launcher ---------------------------------------------------
extern "C" void kernel_launch(void* const* d_in, const int* in_sizes, int n_in,
                              void* d_out, int out_size, void* d_ws, size_t ws_size,
                              hipStream_t stream) {
  const float* x   = (const float*)d_in[0];
  const int*   msk = (const int*)d_in[1];
  const float* pos = (const float*)d_in[2];
  const float* wq  = (const float*)d_in[3];
  const float* bq  = (const float*)d_in[4];
  const float* wk  = (const float*)d_in[5];
  const float* bk  = (const float*)d_in[6];
  const float* wv  = (const float*)d_in[7];
  const float* bv  = (const float*)d_in[8];
  float* out = (float*)d_out;

  char* ws = (char*)d_ws;
  // layout: xb 8M | wb 6M | qkv(Q+K) 16M | posb 16M | vt 8M | OP0 16M | LP 512K
  unsigned short* xb   = (unsigned short*)(ws);
  unsigned short* wb   = (unsigned short*)(ws + 8388608);
  unsigned short* qkv  = (unsigned short*)(ws + 14680064);
  unsigned short* posb = (unsigned short*)(ws + 31457280);
  unsigned short* vt   = (unsigned short*)(ws + 48234496);
  float*          op0  = (float*)(ws + 56623104);
  float*          lp   = (float*)(ws + 73400320);

  cvt_all<<<7680, 256, 0, stream>>>(x, wq, wk, wv, pos, msk, xb, wb, posb);

  qkv_gemm<<<dim3(D_ / 128, (B_ * S_) / 128, 3), 256, 0, stream>>>(
      xb, wb, bq, bk, bv, qkv, vt);

  attn_kernel<<<dim3(H_, S_ / 64, B_ * NSPLIT_), 256, 0, stream>>>(
      qkv, qkv + (size_t)B_ * S_ * D_, vt, posb, op0, lp, out);

  combine_kernel<<<(B_ * S_ * D_) / (256 * 8), 256, 0, stream>>>(op0, lp, out);
}

// Round 9
// 118.639 us; speedup vs baseline: 1.0964x; 1.0964x over previous
//
#include <hip/hip_runtime.h>

#define B_ 2
#define S_ 2048
#define D_ 1024
#define H_ 16
#define HW_ 64
#define NT_ (S_ / 64)

typedef __attribute__((ext_vector_type(8))) short s16x8;
typedef __attribute__((ext_vector_type(4))) float f32x4;
typedef __attribute__((ext_vector_type(2))) unsigned int u32x2;
typedef __attribute__((ext_vector_type(4))) unsigned int u32x4;

__device__ __forceinline__ unsigned short f2bf(float f) {
  unsigned int x = __builtin_bit_cast(unsigned int, f);
  x += 0x7fffu + ((x >> 16) & 1u);
  return (unsigned short)(x >> 16);
}
__device__ __forceinline__ float bf2f(unsigned short u) {
  unsigned int x = ((unsigned int)u) << 16;
  return __builtin_bit_cast(float, x);
}
__device__ __forceinline__ unsigned int cvtpk_bf16(float lo, float hi) {
  unsigned int r;
  asm("v_cvt_pk_bf16_f32 %0, %1, %2" : "=v"(r) : "v"(lo), "v"(hi));
  return r;
}
__device__ __forceinline__ void gload16(const void* g, void* l) {
  __builtin_amdgcn_global_load_lds(
      (const __attribute__((address_space(1))) unsigned int*)g,
      (__attribute__((address_space(3))) unsigned int*)l, 16, 0, 0);
}

// ---------------- unified convert: x | wq/wk/wv | pos+mask ------------------
__global__ __launch_bounds__(256) void cvt_all(const float* __restrict__ x,
                                               const float* __restrict__ wq,
                                               const float* __restrict__ wk,
                                               const float* __restrict__ wv,
                                               const float* __restrict__ pos,
                                               const int* __restrict__ mask,
                                               unsigned short* __restrict__ xb,
                                               unsigned short* __restrict__ wb,
                                               unsigned short* __restrict__ posb) {
  const int blk = blockIdx.x;
  if (blk < 2048) {
    int i = blk * 256 + threadIdx.x;
    const float4* s = (const float4*)x;
    float4 a = s[2 * i], b = s[2 * i + 1];
    s16x8 o;
    o[0] = (short)f2bf(a.x); o[1] = (short)f2bf(a.y);
    o[2] = (short)f2bf(a.z); o[3] = (short)f2bf(a.w);
    o[4] = (short)f2bf(b.x); o[5] = (short)f2bf(b.y);
    o[6] = (short)f2bf(b.z); o[7] = (short)f2bf(b.w);
    ((s16x8*)xb)[i] = o;
  } else if (blk < 3584) {
    int blk2 = blk - 2048;
    const float* src = (blk2 < 512) ? wq : (blk2 < 1024) ? wk : wv;
    int i = (blk2 & 511) * 256 + threadIdx.x;
    const float4* s = (const float4*)src;
    float4 a = s[2 * i], b = s[2 * i + 1];
    s16x8 o;
    o[0] = (short)f2bf(a.x); o[1] = (short)f2bf(a.y);
    o[2] = (short)f2bf(a.z); o[3] = (short)f2bf(a.w);
    o[4] = (short)f2bf(b.x); o[5] = (short)f2bf(b.y);
    o[6] = (short)f2bf(b.z); o[7] = (short)f2bf(b.w);
    ((s16x8*)wb)[(size_t)(blk2 >> 9) * (D_ * D_ / 8) + i] = o;
  } else {
    int i = (blk - 3584) * 256 + threadIdx.x;  // 8 elems per thread
    int e = i * 8;
    int b = e / (S_ * S_);
    int k = e & (S_ - 1);
    const float4* s = (const float4*)pos;
    float4 a = s[2 * i], c = s[2 * i + 1];
    const int* mrow = mask + b * S_ + k;
    const float L2E = 1.4426950408889634f;
    float f[8] = {a.x, a.y, a.z, a.w, c.x, c.y, c.z, c.w};
    s16x8 o;
#pragma unroll
    for (int j = 0; j < 8; ++j) {
      float bias = mrow[j] ? 0.0f : -14427.0f;
      o[j] = (short)f2bf(f[j] * L2E + bias);
    }
    ((s16x8*)posb)[i] = o;
  }
}

// ---------------- QKV projection GEMM: C = X(bf16) * W^T + bias -------------
// mat==0 (Q): output pre-scaled by 0.125*log2e.  mat==2 (V): operands swapped
// -> epilogue writes V directly TRANSPOSED to VT[b][h][d][s].
__global__ __launch_bounds__(256) void qkv_gemm(const unsigned short* __restrict__ X,
                                                const unsigned short* __restrict__ W3,
                                                const float* __restrict__ bq,
                                                const float* __restrict__ bk,
                                                const float* __restrict__ bv,
                                                unsigned short* __restrict__ O3,
                                                unsigned short* __restrict__ VT) {
  const int mat = blockIdx.z;
  const unsigned short* Wp = W3 + (size_t)mat * (D_ * D_);
  const float* bias = (mat == 0) ? bq : (mat == 1) ? bk : bv;
  unsigned short* Op = O3 + (size_t)mat * ((size_t)B_ * S_ * D_);

  const int bm = blockIdx.y * 128, bn = blockIdx.x * 128;
  const int tid = threadIdx.x;
  const int lane = tid & 63, w = tid >> 6;
  const int wr = (w >> 1) * 64, wc = (w & 1) * 64;
  const int l15 = lane & 15, lh = lane >> 4;

  __shared__ __align__(16) unsigned short Al[128 * 64];
  __shared__ __align__(16) unsigned short Wl[128 * 64];

  f32x4 acc[4][4];
#pragma unroll
  for (int m = 0; m < 4; ++m)
#pragma unroll
    for (int n = 0; n < 4; ++n) acc[m][n] = (f32x4){0.f, 0.f, 0.f, 0.f};

  const int srow = lane >> 3;
  const int scol = ((lane & 7) ^ srow) * 8;
  const int i0 = w * 4;

  for (int k0 = 0; k0 < D_; k0 += 64) {
    __syncthreads();
#pragma unroll
    for (int i2 = 0; i2 < 4; ++i2) {
      int i = i0 + i2;
      int row = 8 * i + srow;
      gload16(X + (size_t)(bm + row) * D_ + k0 + scol, Al + i * 512);
      gload16(Wp + (size_t)(bn + row) * D_ + k0 + scol, Wl + i * 512);
    }
    __syncthreads();
#pragma unroll
    for (int kb = 0; kb < 2; ++kb) {
      const int cs = (kb * 32 + lh * 8) ^ ((l15 & 7) * 8);
      s16x8 af[4], wf[4];
#pragma unroll
      for (int m = 0; m < 4; ++m)
        af[m] = *(const s16x8*)(Al + (wr + m * 16 + l15) * 64 + cs);
#pragma unroll
      for (int n = 0; n < 4; ++n)
        wf[n] = *(const s16x8*)(Wl + (wc + n * 16 + l15) * 64 + cs);
      if (mat == 2) {
#pragma unroll
        for (int m = 0; m < 4; ++m)
#pragma unroll
          for (int n = 0; n < 4; ++n)
            acc[m][n] =
                __builtin_amdgcn_mfma_f32_16x16x32_bf16(wf[n], af[m], acc[m][n], 0, 0, 0);
      } else {
#pragma unroll
        for (int m = 0; m < 4; ++m)
#pragma unroll
          for (int n = 0; n < 4; ++n)
            acc[m][n] =
                __builtin_amdgcn_mfma_f32_16x16x32_bf16(af[m], wf[n], acc[m][n], 0, 0, 0);
      }
    }
  }

  if (mat == 2) {
#pragma unroll
    for (int n = 0; n < 4; ++n) {
      f32x4 b4 = *(const f32x4*)(bias + bn + wc + n * 16 + lh * 4);
#pragma unroll
      for (int m = 0; m < 4; ++m) {
        int t = bm + wr + m * 16 + l15;  // global token
        int bb = t >> 11, s = t & (S_ - 1);
#pragma unroll
        for (int r = 0; r < 4; ++r) {
          int f = bn + wc + n * 16 + lh * 4 + r;  // global feature
          VT[((size_t)(bb * H_ + (f >> 6)) * HW_ + (f & 63)) * S_ + s] =
              f2bf(acc[m][n][r] + b4[r]);
        }
      }
    }
  } else {
    const float oscale = (mat == 0) ? 0.18033688751411092f : 1.0f;  // 0.125*log2e
#pragma unroll
    for (int n = 0; n < 4; ++n) {
      int col = bn + wc + n * 16 + l15;
      float bval = bias[col];
#pragma unroll
      for (int m = 0; m < 4; ++m) {
        int row0 = bm + wr + m * 16 + lh * 4;
#pragma unroll
        for (int r = 0; r < 4; ++r)
          Op[(size_t)(row0 + r) * D_ + col] = f2bf((acc[m][n][r] + bval) * oscale);
      }
    }
  }
}

// ---------------- fused flash attention (quadrant decomposition) ------------
// grid (H, S/64, B), 256 threads = 4 waves. Wave w owns q-half qp=w>>1
// (32 q-rows) x key-half kh=w&1 (32 keys of each 64-key tile) -> each wave
// reads HALF the K rows + HALF the V cols (8 ds_read_b128/tile vs 16).
// Max-free softmax (log2-domain, additive partials). Epilogue: odd waves
// (kh=1) push O/l partials through LDS; even waves combine+normalize+store.
__global__ __launch_bounds__(256, 4) void attn_kernel(
    const unsigned short* __restrict__ Q,
    const unsigned short* __restrict__ K,
    const unsigned short* __restrict__ VT,
    const unsigned short* __restrict__ POSM,
    float* __restrict__ OUT) {
  const int h = blockIdx.x, qt = blockIdx.y, b = blockIdx.z;
  const int tid = threadIdx.x;
  const int lane = tid & 63, w = tid >> 6;
  const int l15 = lane & 15, lh = lane >> 4;
  const int qp = w >> 1, kh = w & 1;

  __shared__ __align__(16) unsigned short Kl[2][64 * 64];  // [key][d], swizzled
  __shared__ __align__(16) unsigned short Vl[2][64 * 64];  // [d][key], swizzled

  // storage swizzle: elem-group g(0..7) ^= (row&3) | ((row&8)>>1)
  const int swzk = ((l15 & 3) | (((l15 >> 2) & 1) << 2)) * 8;  // K rows: 8*(l15>>2)+(l15&3)+...
  const int swzv = ((l15 & 3) | ((l15 & 8) >> 1)) * 8;         // V rows: dblk*16+l15
  const int rowbase = kh * 32 + 8 * (l15 >> 2) + (l15 & 3);    // K physical row base

  const int srow = lane >> 3;
  const int scol = ((lane & 7) ^ ((lane >> 3) & 3) ^ ((w & 1) << 2)) * 8;
  const unsigned short* Kbase = K + (size_t)b * S_ * D_ + h * HW_;
  const unsigned short* Vbase = VT + ((size_t)(b * H_ + h) * HW_) * S_;

  auto stage = [&](int buf, int kt) {
    const int k0 = kt * 64;
#pragma unroll
    for (int i = 0; i < 2; ++i) {
      const int rb = i * 32 + w * 8;
      gload16(Kbase + (size_t)(k0 + rb + srow) * D_ + scol, &Kl[buf][rb * 64]);
      gload16(Vbase + (size_t)(rb + srow) * S_ + k0 + scol, &Vl[buf][rb * 64]);
    }
  };

  const int q0 = qt * 64 + qp * 32;
  const int qg0 = q0 + l15, qg1 = q0 + 16 + l15;  // lane's two q rows
  // pos row pointers (col base: this wave's key half + lane's 8-key slot)
  const unsigned short* Pp0 = POSM + (size_t)(b * S_ + qg0) * S_ + kh * 32 + lh * 8;
  const unsigned short* Pp1 = POSM + (size_t)(b * S_ + qg1) * S_ + kh * 32 + lh * 8;

  // prologue: pos tile 0 + stage tile 0 + Q frags
  s16x8 pm_c[2], pm_n[2];
  pm_c[0] = *(const s16x8*)(Pp0);
  pm_c[1] = *(const s16x8*)(Pp1);
  stage(0, 0);

  s16x8 qf[2][2];
  {
    const unsigned short* qp0 = Q + (size_t)(b * S_ + qg0) * D_ + h * HW_ + lh * 8;
    const unsigned short* qp1 = Q + (size_t)(b * S_ + qg1) * D_ + h * HW_ + lh * 8;
    qf[0][0] = *(const s16x8*)qp0;
    qf[0][1] = *(const s16x8*)(qp0 + 32);
    qf[1][0] = *(const s16x8*)qp1;
    qf[1][1] = *(const s16x8*)(qp1 + 32);
  }

  f32x4 Oc[2][4];  // [qsub][dblk], O^T: d = dblk*16+lh*4+r, q = q0+s*16+l15
#pragma unroll
  for (int s = 0; s < 2; ++s)
#pragma unroll
    for (int n = 0; n < 4; ++n) Oc[s][n] = (f32x4){0.f, 0.f, 0.f, 0.f};
  float lsq[2] = {0.f, 0.f};

  for (int kt = 0; kt < NT_; ++kt) {
    const int cur = kt & 1;

    if (kt + 1 < NT_) {
      pm_n[0] = *(const s16x8*)(Pp0 + (kt + 1) * 64);
      pm_n[1] = *(const s16x8*)(Pp1 + (kt + 1) * 64);
      stage(cur ^ 1, kt + 1);
      // queue oldest->newest: [stage(kt) 4] [pos(kt+1) 2] [stage(kt+1) 4]
      asm volatile("s_waitcnt vmcnt(6)" ::: "memory");
    } else {
      asm volatile("s_waitcnt vmcnt(0)" ::: "memory");
    }
    asm volatile("s_barrier" ::: "memory");

    const unsigned short* Kc = Kl[cur];
    const unsigned short* Vc = Vl[cur];

    // K frags for this wave's 32-key half (permuted: key_rel = lh*8+n*4+r)
    s16x8 kf0[2], kf1[2];
#pragma unroll
    for (int n = 0; n < 2; ++n) {
      const unsigned short* kr = Kc + (rowbase + n * 4) * 64;
      kf0[n] = *(const s16x8*)(kr + ((lh * 8) ^ swzk));
      kf1[n] = *(const s16x8*)(kr + ((32 + lh * 8) ^ swzk));
    }

    // QK^T: sc[s][n][r] -> q = q0+s*16+l15, key = kh*32 + lh*8 + n*4 + r
    f32x4 sc[2][2];
    __builtin_amdgcn_s_setprio(1);
#pragma unroll
    for (int s = 0; s < 2; ++s)
#pragma unroll
      for (int n = 0; n < 2; ++n) {
        f32x4 c;
#pragma unroll
        for (int r = 0; r < 4; ++r)
          c[r] = bf2f((unsigned short)pm_c[s][n * 4 + r]);
        c = __builtin_amdgcn_mfma_f32_16x16x32_bf16(kf0[n], qf[s][0], c, 0, 0, 0);
        c = __builtin_amdgcn_mfma_f32_16x16x32_bf16(kf1[n], qf[s][1], c, 0, 0, 0);
        sc[s][n] = c;
      }
    __builtin_amdgcn_s_setprio(0);

    // p = exp2(score); accumulate per-q-row partial sums
#pragma unroll
    for (int s = 0; s < 2; ++s)
#pragma unroll
      for (int n = 0; n < 2; ++n)
#pragma unroll
        for (int r = 0; r < 4; ++r) {
          float p = __builtin_amdgcn_exp2f(sc[s][n][r]);
          sc[s][n][r] = p;
          lsq[s] += p;
        }

    // PV: per qsub, B-frag (keys lh*8+0..7) built in registers; A = V frags
    __builtin_amdgcn_s_setprio(1);
    s16x8 vf[4];
#pragma unroll
    for (int n = 0; n < 4; ++n)
      vf[n] = *(const s16x8*)(Vc + (n * 16 + l15) * 64 + ((kh * 32 + lh * 8) ^ swzv));
#pragma unroll
    for (int s = 0; s < 2; ++s) {
      u32x4 pw;
      pw[0] = cvtpk_bf16(sc[s][0][0], sc[s][0][1]);
      pw[1] = cvtpk_bf16(sc[s][0][2], sc[s][0][3]);
      pw[2] = cvtpk_bf16(sc[s][1][0], sc[s][1][1]);
      pw[3] = cvtpk_bf16(sc[s][1][2], sc[s][1][3]);
      s16x8 pf = __builtin_bit_cast(s16x8, pw);
#pragma unroll
      for (int n = 0; n < 4; ++n)
        Oc[s][n] = __builtin_amdgcn_mfma_f32_16x16x32_bf16(vf[n], pf, Oc[s][n], 0, 0, 0);
    }
    __builtin_amdgcn_s_setprio(0);

    asm volatile("s_barrier" ::: "memory");

    pm_c[0] = pm_n[0];
    pm_c[1] = pm_n[1];
  }

  // ---- epilogue: cross-wave (key-half) combine via LDS ----
  // intra-wave l reduction (over lh groups)
#pragma unroll
  for (int s = 0; s < 2; ++s) {
    lsq[s] += __shfl_xor(lsq[s], 16, 64);
    lsq[s] += __shfl_xor(lsq[s], 32, 64);
  }

  __syncthreads();  // all tile reads complete before Kl/Vl reuse
  f32x4* xO = (f32x4*)Kl;   // 16 KB: [qp][s][dblk][lane] f32x4
  float* xL = (float*)Vl;   // [qp][s][l15]
  if (kh) {
#pragma unroll
    for (int s = 0; s < 2; ++s) {
#pragma unroll
      for (int n = 0; n < 4; ++n)
        xO[((qp * 2 + s) * 4 + n) * 64 + lane] = Oc[s][n];
      if (lh == 0) xL[(qp * 2 + s) * 16 + l15] = lsq[s];
    }
  }
  __syncthreads();
  if (!kh) {
#pragma unroll
    for (int s = 0; s < 2; ++s) {
      float ltot = lsq[s] + xL[(qp * 2 + s) * 16 + l15];
      float inv = 1.0f / ltot;
      int qg = q0 + s * 16 + l15;
      float* outp = OUT + (size_t)(b * S_ + qg) * D_ + h * HW_ + lh * 4;
#pragma unroll
      for (int n = 0; n < 4; ++n) {
        f32x4 o = xO[((qp * 2 + s) * 4 + n) * 64 + lane];
#pragma unroll
        for (int r = 0; r < 4; ++r) o[r] = (o[r] + Oc[s][n][r]) * inv;
        *(f32x4*)(outp + n * 16) = o;
      }
    }
  }
}

// ---------------- launcher ---------------------------------------------------
extern "C" void kernel_launch(void* const* d_in, const int* in_sizes, int n_in,
                              void* d_out, int out_size, void* d_ws, size_t ws_size,
                              hipStream_t stream) {
  const float* x   = (const float*)d_in[0];
  const int*   msk = (const int*)d_in[1];
  const float* pos = (const float*)d_in[2];
  const float* wq  = (const float*)d_in[3];
  const float* bq  = (const float*)d_in[4];
  const float* wk  = (const float*)d_in[5];
  const float* bk  = (const float*)d_in[6];
  const float* wv  = (const float*)d_in[7];
  const float* bv  = (const float*)d_in[8];
  float* out = (float*)d_out;

  char* ws = (char*)d_ws;
  // layout: xb 8M | wb 6M | qkv(Q+K) 16M | posb 16M | vt 8M
  unsigned short* xb   = (unsigned short*)(ws);
  unsigned short* wb   = (unsigned short*)(ws + 8388608);
  unsigned short* qkv  = (unsigned short*)(ws + 14680064);
  unsigned short* posb = (unsigned short*)(ws + 31457280);
  unsigned short* vt   = (unsigned short*)(ws + 48234496);

  cvt_all<<<7680, 256, 0, stream>>>(x, wq, wk, wv, pos, msk, xb, wb, posb);

  qkv_gemm<<<dim3(D_ / 128, (B_ * S_) / 128, 3), 256, 0, stream>>>(
      xb, wb, bq, bk, bv, qkv, vt);

  attn_kernel<<<dim3(H_, S_ / 64, B_), 256, 0, stream>>>(
      qkv, qkv + (size_t)B_ * S_ * D_, vt, posb, out);
}